// Round 2
// baseline (368.660 us; speedup 1.0000x reference)
//
#include <hip/hip_runtime.h>
#include <hip/hip_bf16.h>

// out[b] = mean_x( 0.5 - 0.5*tanh((x - bins[b]) * 2/bw) ), bw = 0.0625,
//          bins[b] = -2 + bw*b, b in [0,64)
// With t = (x+2)*16 (bin coordinate), per-element contribution to bin b is
//   sigma(4*(b - t)),  sigma = logistic.
// sigma saturates to {0,1} within |b - t| >= 5, so a fine histogram of t
// (cell = 1/64 bin over t in [-5, 69)) is a sufficient statistic to ~1e-5.

#define NCELLS (74 * 64)        // 4736 cells, t in [-5, 69), width 1/64
#define HIST_BLOCKS 1024
#define HIST_THREADS 256

__global__ void __launch_bounds__(HIST_THREADS)
hist_kernel(const float* __restrict__ x, unsigned* __restrict__ ghist, int n)
{
    __shared__ unsigned hist[NCELLS];
    for (int i = threadIdx.x; i < NCELLS; i += HIST_THREADS) hist[i] = 0u;
    __syncthreads();

    const int n4 = n >> 2;
    const float4* __restrict__ x4 = (const float4*)x;
    const int gid    = blockIdx.x * HIST_THREADS + threadIdx.x;
    const int stride = gridDim.x * HIST_THREADS;

    // cell index: f = floor((t + 5) * 64) = floor(x*1024 + 2368)  -- one FMA
    for (int i = gid; i < n4; i += stride) {
        float4 v = x4[i];
        {
            int f = (int)floorf(fmaf(v.x, 1024.0f, 2368.0f));
            f = min(max(f, 0), NCELLS - 1);
            atomicAdd(&hist[f], 1u);
        }
        {
            int f = (int)floorf(fmaf(v.y, 1024.0f, 2368.0f));
            f = min(max(f, 0), NCELLS - 1);
            atomicAdd(&hist[f], 1u);
        }
        {
            int f = (int)floorf(fmaf(v.z, 1024.0f, 2368.0f));
            f = min(max(f, 0), NCELLS - 1);
            atomicAdd(&hist[f], 1u);
        }
        {
            int f = (int)floorf(fmaf(v.w, 1024.0f, 2368.0f));
            f = min(max(f, 0), NCELLS - 1);
            atomicAdd(&hist[f], 1u);
        }
    }

    // scalar tail (N is divisible by 4 for this problem, but be safe)
    if (blockIdx.x == 0) {
        int tail = n & 3;
        if (threadIdx.x < tail) {
            float v = x[n4 * 4 + threadIdx.x];
            int f = (int)floorf(fmaf(v, 1024.0f, 2368.0f));
            f = min(max(f, 0), NCELLS - 1);
            atomicAdd(&hist[f], 1u);
        }
    }

    __syncthreads();
    for (int i = threadIdx.x; i < NCELLS; i += HIST_THREADS) {
        unsigned v = hist[i];
        if (v) atomicAdd(&ghist[i], v);
    }
}

__global__ void __launch_bounds__(256)
bins_kernel(const unsigned* __restrict__ ghist, float* __restrict__ out, float invN)
{
    const int b = blockIdx.x;           // 64 blocks, one per output bin
    double sum = 0.0;
    for (int f = threadIdx.x; f < NCELLS; f += 256) {
        unsigned h = ghist[f];
        if (h) {
            float t = -5.0f + ((float)f + 0.5f) * (1.0f / 64.0f); // cell center
            float z = 4.0f * ((float)b - t);
            float s = 1.0f / (1.0f + __expf(-z));  // saturates cleanly: inf -> 0
            sum += (double)h * (double)s;
        }
    }
    __shared__ double sd[256];
    sd[threadIdx.x] = sum;
    __syncthreads();
    for (int ofs = 128; ofs > 0; ofs >>= 1) {
        if (threadIdx.x < ofs) sd[threadIdx.x] += sd[threadIdx.x + ofs];
        __syncthreads();
    }
    if (threadIdx.x == 0) out[b] = (float)(sd[0] * (double)invN);
}

extern "C" void kernel_launch(void* const* d_in, const int* in_sizes, int n_in,
                              void* d_out, int out_size, void* d_ws, size_t ws_size,
                              hipStream_t stream)
{
    const float* x = (const float*)d_in[0];
    const int n = in_sizes[0];
    unsigned* ghist = (unsigned*)d_ws;

    // d_ws is re-poisoned to 0xAA before every call; zero the histogram.
    hipMemsetAsync(d_ws, 0, NCELLS * sizeof(unsigned), stream);

    hist_kernel<<<HIST_BLOCKS, HIST_THREADS, 0, stream>>>(x, ghist, n);
    bins_kernel<<<64, 256, 0, stream>>>(ghist, (float*)d_out, 1.0f / (float)n);
}